// Round 1
// baseline (6907.287 us; speedup 1.0000x reference)
//
#include <hip/hip_runtime.h>
#include <stdint.h>

#define Bsz  128
#define NUMS 128
#define SEQn 256
#define Hn   1024
#define PRED 96
#define G4H  4096

typedef __attribute__((ext_vector_type(8))) short bf16x8;
typedef __attribute__((ext_vector_type(4))) float f32x4;

__device__ __forceinline__ unsigned short f2bf(float x){
  union { float f; unsigned u; } v; v.f = x;
  return (unsigned short)((v.u + 0x7FFFu + ((v.u >> 16) & 1u)) >> 16);
}

// ---- pack x: [B][NUMS][SEQ] f32 -> xp [SEQ][B][NUMS] bf16 (LDS transpose) ----
__global__ void pack_x_kernel(const float* __restrict__ x, unsigned short* __restrict__ xp){
  __shared__ float tile[64][65];
  const int t0 = blockIdx.x * 64, n0 = blockIdx.y * 64, b = blockIdx.z;
  const int tid = threadIdx.x;
  const int c = tid & 63, r = tid >> 6;
  #pragma unroll
  for (int i = 0; i < 16; i++){
    int n = r + i*4;
    tile[n][c] = x[((size_t)b*NUMS + n0 + n)*SEQn + t0 + c];
  }
  __syncthreads();
  #pragma unroll
  for (int i = 0; i < 16; i++){
    int t = r + i*4;
    xp[((size_t)(t0+t)*Bsz + b)*NUMS + n0 + c] = f2bf(tile[c][t]);
  }
}

// ---- pack W [K][4096] f32 -> Wpk[cgg][kst][lane][8] bf16 (exact MFMA B-frag order)
// cgg = nb*4 + gate (nb = hidden-16 slice), lane: n = lane&15 -> jj, k = kst*32+(lane>>4)*8+e
__global__ void pack_w_kernel(const float* __restrict__ W, unsigned short* __restrict__ Wpk, int KST){
  const int u = blockIdx.x * blockDim.x + threadIdx.x;
  if (u >= 256*KST*64) return;
  const int lane = u & 63;
  const int kst  = (u >> 6) % KST;
  const int cgg  = (u >> 6) / KST;
  const int nb = cgg >> 2, gate = cgg & 3;
  const int col = gate*Hn + nb*16 + (lane & 15);
  const int kbase = kst*32 + (lane >> 4)*8;
  unsigned short tmp[8];
  #pragma unroll
  for (int e = 0; e < 8; e++) tmp[e] = f2bf(W[(size_t)(kbase+e)*G4H + col]);
  ((ulonglong2*)Wpk)[u] = *(const ulonglong2*)tmp;
}

__global__ void zero_kernel(unsigned short* __restrict__ h0, float* __restrict__ c){
  int i = blockIdx.x*256 + threadIdx.x;
  if (i < Bsz*Hn){ h0[i] = 0; c[i] = 0.0f; }
}

// ---- one LSTM timestep: z = [A1|A2] @ W + b ; gates ; c,h update ----
// Grid 256 = 4 mb (32 rows) x 64 nb (16 hidden j). 512 thr = 8 waves = 2 mf x 4 gates.
template<int K1, int KTOT>
__global__ __launch_bounds__(512, 2)
void step_kernel(const unsigned short* __restrict__ A1,   // [B][K1]  bf16
                 const unsigned short* __restrict__ A2,   // [B][H]   bf16 (h_prev)
                 const unsigned short* __restrict__ Wpk,  // packed B-frags
                 const float* __restrict__ bias,          // [4096] original order
                 float* __restrict__ cst,                 // [B][H] f32, in-place
                 unsigned short* __restrict__ hbf_out,    // [B][H] bf16
                 float* __restrict__ hf_out)              // [B][H] f32 or null
{
  constexpr int KST_TOT = KTOT/32;
  constexpr int NCH = (KTOT + 511)/512;
  __shared__ union SM {
    unsigned short a[2][32*512];   // 2 x 32KB A chunk buffers
    float e[4*32*18];              // epilogue acc exchange (aliased; used after last barrier)
  } sm;
  const int tid = threadIdx.x;
  const int w = tid >> 6, l = tid & 63;
  const int mb = blockIdx.x & 3, nb = blockIdx.x >> 2;
  const int mf = w & 1, cgi = w >> 1;          // cgi = gate
  const int cgg = nb*4 + cgi;
  const int lrow = l & 15, lg = l >> 4;

  f32x4 acc = {0.f, 0.f, 0.f, 0.f};

  // async stage chunk ch (width kw) into buffer bb; XOR-swizzled 16B units
  auto stage = [&](int bb, int ch, int kw, int lu){
    const int nissue = kw >> 4;                // (32 rows * kw/8 units)/64 lanes
    for (int i = w; i < nissue; i += 8){
      const int s = i*64 + l;
      const int row = s >> lu;
      const int uu  = s & ((1 << lu) - 1);
      const int ku  = uu ^ (row & 7);
      const int kg  = ch*512 + ku*8;
      const int R   = mb*32 + row;
      const unsigned short* src = (kg < K1) ? (A1 + (size_t)R*K1 + kg)
                                            : (A2 + (size_t)R*Hn + (kg - K1));
      __builtin_amdgcn_global_load_lds(
        (const __attribute__((address_space(1))) void*)src,
        (__attribute__((address_space(3))) void*)&sm.a[bb][i*512],
        16, 0, 0);
    }
  };

  {
    constexpr int kw0 = (KTOT >= 512) ? 512 : KTOT;
    stage(0, 0, kw0, (kw0 == 512) ? 6 : 4);
  }
  __syncthreads();

  #pragma unroll
  for (int ch = 0; ch < NCH; ch++){
    const int bb = ch & 1;
    const int kw = ((KTOT - ch*512) >= 512) ? 512 : (KTOT - ch*512);
    if (ch + 1 < NCH){
      const int kwn = ((KTOT - (ch+1)*512) >= 512) ? 512 : (KTOT - (ch+1)*512);
      stage(bb ^ 1, ch+1, kwn, (kwn == 512) ? 6 : 4);
    }
    const int UPR  = kw >> 3;
    const int kstc = kw >> 5;
    const int row  = mf*16 + lrow;
    const unsigned short* wp = Wpk + ((size_t)(cgg*KST_TOT + ch*16)*64 + l)*8;
    #pragma unroll
    for (int ks = 0; ks < kstc; ks++){
      const int unit = ks*4 + lg;
      bf16x8 af = *(const bf16x8*)&sm.a[bb][(row*UPR + (unit ^ (row & 7)))*8];
      bf16x8 bw = *(const bf16x8*)(wp + (size_t)ks*512);
      acc = __builtin_amdgcn_mfma_f32_16x16x32_bf16(af, bw, acc, 0, 0, 0);
    }
    __syncthreads();
  }

  // dump acc (C layout: col=lane&15, row=(lane>>4)*4+reg) to LDS for gate exchange
  {
    const int jj = l & 15;
    #pragma unroll
    for (int r = 0; r < 4; r++){
      const int row = mf*16 + lg*4 + r;
      sm.e[(cgi*32 + row)*18 + jj] = acc[r];
    }
  }
  __syncthreads();
  {
    const int row = tid >> 4, jj = tid & 15;
    const int R = mb*32 + row;
    const int J = nb*16 + jj;
    const float zi = sm.e[(0*32+row)*18 + jj] + bias[0*Hn + J];
    const float zf = sm.e[(1*32+row)*18 + jj] + bias[1*Hn + J];
    const float zo = sm.e[(2*32+row)*18 + jj] + bias[2*Hn + J];
    const float zg = sm.e[(3*32+row)*18 + jj] + bias[3*Hn + J];
    const float gi = 1.f/(1.f + __expf(-zi));
    const float gf = 1.f/(1.f + __expf(-zf));
    const float go = 1.f/(1.f + __expf(-zo));
    const float gg = tanhf(zg);
    const size_t idx = (size_t)R*Hn + J;
    const float cn = gf * cst[idx] + gi * gg;
    cst[idx] = cn;
    const float hn = go * tanhf(cn);
    hbf_out[idx] = f2bf(hn);
    if (hf_out) hf_out[idx] = hn;
  }
}

// ---- final FC + copy h,c to d_out ----
__global__ __launch_bounds__(256)
void fc_out_kernel(const float* __restrict__ hf, const float* __restrict__ cst,
                   const float* __restrict__ fcw, const float* __restrict__ fcb,
                   float* __restrict__ dout){
  __shared__ float hrow[Hn];
  const int b = blockIdx.x, tid = threadIdx.x;
  for (int i = tid; i < Hn; i += 256) hrow[i] = hf[(size_t)b*Hn + i];
  __syncthreads();
  if (tid < PRED){
    float a = fcb[tid];
    for (int k = 0; k < Hn; k++) a += hrow[k] * fcw[(size_t)k*PRED + tid];
    dout[(size_t)b*PRED + tid] = tanhf(a);
  }
  for (int i = tid; i < Hn; i += 256){
    dout[Bsz*PRED + (size_t)b*Hn + i] = hf[(size_t)b*Hn + i];
    dout[Bsz*PRED + (size_t)Bsz*Hn + (size_t)b*Hn + i] = cst[(size_t)b*Hn + i];
  }
}

extern "C" void kernel_launch(void* const* d_in, const int* in_sizes, int n_in,
                              void* d_out, int out_size, void* d_ws, size_t ws_size,
                              hipStream_t stream){
  const float* x   = (const float*)d_in[0];
  const float* W0  = (const float*)d_in[1];
  const float* b0  = (const float*)d_in[2];
  const float* W1  = (const float*)d_in[3];
  const float* b1  = (const float*)d_in[4];
  const float* fcw = (const float*)d_in[5];
  const float* fcb = (const float*)d_in[6];
  float* dout = (float*)d_out;

  char* p = (char*)d_ws;
  auto alloc = [&](size_t bytes)->void*{
    void* r = (void*)p; p += (bytes + 255) & ~(size_t)255; return r;
  };
  unsigned short* xp   = (unsigned short*)alloc((size_t)SEQn*Bsz*NUMS*2);      // 8 MB
  unsigned short* Wpk0 = (unsigned short*)alloc((size_t)256*36*64*8*2);        // 9 MB
  unsigned short* Wpk1 = (unsigned short*)alloc((size_t)256*64*64*8*2);        // 16 MB
  unsigned short* H0   = (unsigned short*)alloc((size_t)(SEQn+1)*Bsz*Hn*2);    // 64.25 MB
  unsigned short* h1   = (unsigned short*)alloc((size_t)2*Bsz*Hn*2);           // 0.5 MB
  float* cst = (float*)alloc((size_t)Bsz*Hn*4);
  float* hf  = (float*)alloc((size_t)Bsz*Hn*4);

  pack_x_kernel<<<dim3(SEQn/64, NUMS/64, Bsz), dim3(256), 0, stream>>>(x, xp);
  pack_w_kernel<<<dim3((256*36*64 + 255)/256), dim3(256), 0, stream>>>(W0, Wpk0, 36);
  pack_w_kernel<<<dim3((256*64*64 + 255)/256), dim3(256), 0, stream>>>(W1, Wpk1, 64);
  zero_kernel<<<dim3((Bsz*Hn + 255)/256), dim3(256), 0, stream>>>(H0, cst);

  // layer 0: A = [x_t (128) | h_prev (1024)], h chain lives in H0 ring (slot t -> t+1)
  for (int t = 0; t < SEQn; t++){
    step_kernel<128, 1152><<<dim3(256), dim3(512), 0, stream>>>(
        xp + (size_t)t*Bsz*NUMS,
        H0 + (size_t)t*Bsz*Hn,
        Wpk0, b0, cst,
        H0 + (size_t)(t+1)*Bsz*Hn,
        (float*)nullptr);
  }
  // layer 1: A = [h0_t (1024) | h_prev (1024)]; initial h = layer-0 final (H0 slot 256)
  for (int t = 0; t < SEQn; t++){
    const unsigned short* hprev = (t == 0) ? (H0 + (size_t)SEQn*Bsz*Hn)
                                           : (h1 + (size_t)((t+1)&1)*Bsz*Hn);
    step_kernel<1024, 2048><<<dim3(256), dim3(512), 0, stream>>>(
        H0 + (size_t)(t+1)*Bsz*Hn,
        hprev,
        Wpk1, b1, cst,
        h1 + (size_t)(t&1)*Bsz*Hn,
        hf);
  }
  fc_out_kernel<<<dim3(Bsz), dim3(256), 0, stream>>>(hf, cst, fcw, fcb, dout);
}

// Round 2
// 5711.723 us; speedup vs baseline: 1.2093x; 1.2093x over previous
//
#include <hip/hip_runtime.h>
#include <stdint.h>

#define Bsz  128
#define NUMS 128
#define SEQn 256
#define Hn   1024
#define PRED 96
#define G4H  4096

typedef __attribute__((ext_vector_type(8))) short bf16x8;
typedef __attribute__((ext_vector_type(4))) float f32x4;

__device__ __forceinline__ unsigned short f2bf(float x){
  union { float f; unsigned u; } v; v.f = x;
  return (unsigned short)((v.u + 0x7FFFu + ((v.u >> 16) & 1u)) >> 16);
}
__device__ __forceinline__ float bf2f(unsigned short s){
  union { unsigned u; float f; } v; v.u = ((unsigned)s) << 16; return v.f;
}

// ---- pack x: [B][NUMS][SEQ] f32 -> xp [SEQ][B][NUMS] bf16 (LDS transpose) ----
__global__ void pack_x_kernel(const float* __restrict__ x, unsigned short* __restrict__ xp){
  __shared__ float tile[64][65];
  const int t0 = blockIdx.x * 64, n0 = blockIdx.y * 64, b = blockIdx.z;
  const int tid = threadIdx.x;
  const int c = tid & 63, r = tid >> 6;
  #pragma unroll
  for (int i = 0; i < 16; i++){
    int n = r + i*4;
    tile[n][c] = x[((size_t)b*NUMS + n0 + n)*SEQn + t0 + c];
  }
  __syncthreads();
  #pragma unroll
  for (int i = 0; i < 16; i++){
    int t = r + i*4;
    xp[((size_t)(t0+t)*Bsz + b)*NUMS + n0 + c] = f2bf(tile[c][t]);
  }
}

// ---- pack W rows [row_off, row_off+KST*32) of [Krows][4096] f32 into MFMA B-frag order.
// gate_il=1: cgg=nb*4+gate -> col=gate*Hn+nb*16+(lane&15)   (step kernels)
// gate_il=0: cg linear     -> col=cg*16+(lane&15)           (bulk input GEMM)
__global__ void pack_w_kernel(const float* __restrict__ W, unsigned short* __restrict__ Wpk,
                              int KST, int row_off, int gate_il){
  const int u = blockIdx.x * blockDim.x + threadIdx.x;
  if (u >= 256*KST*64) return;
  const int lane = u & 63;
  const int kst  = (u >> 6) % KST;
  const int cgg  = (u >> 6) / KST;
  int col;
  if (gate_il){ const int nb = cgg >> 2, gate = cgg & 3; col = gate*Hn + nb*16 + (lane & 15); }
  else        { col = cgg*16 + (lane & 15); }
  const int kbase = row_off + kst*32 + (lane >> 4)*8;
  unsigned short tmp[8];
  #pragma unroll
  for (int e = 0; e < 8; e++) tmp[e] = f2bf(W[(size_t)(kbase+e)*G4H + col]);
  ((ulonglong2*)Wpk)[u] = *(const ulonglong2*)tmp;
}

__global__ void zero_kernel(unsigned short* __restrict__ h0, float* __restrict__ c){
  int i = blockIdx.x*256 + threadIdx.x;
  if (i < Bsz*Hn){ h0[i] = 0; c[i] = 0.0f; }
}

// ---- bulk input-projection GEMM: C[32768][4096] = A[32768][1024] @ Wt + bias (bf16 out)
// 128x128 tiles, 256 thr = 4 waves (2x2), each wave 64x64 via 4x4 mfma_16x16x32 frags.
__global__ __launch_bounds__(256, 2)
void in_gemm_kernel(const unsigned short* __restrict__ A,
                    const unsigned short* __restrict__ Bp,   // packed, gate_il=0, KST=32
                    const float* __restrict__ bias,
                    unsigned short* __restrict__ C){
  __shared__ unsigned short sa[2][128*64];
  const int tid = threadIdx.x, w = tid >> 6, l = tid & 63;
  const int bm = blockIdx.x, bn = blockIdx.y;
  const int wm = w & 1, wn = w >> 1;
  const int lrow = l & 15, lg = l >> 4;
  f32x4 acc[4][4] = {};

  auto stage = [&](int bb, int ch){
    for (int i = w; i < 16; i += 4){            // 16 wave-issues x 64 lanes = 1024 x 16B
      const int s = i*64 + l;
      const int row = s >> 3, uu = s & 7, ku = uu ^ (row & 7);
      const unsigned short* src = A + (size_t)(bm*128 + row)*Hn + ch*64 + ku*8;
      __builtin_amdgcn_global_load_lds(
        (const __attribute__((address_space(1))) void*)src,
        (__attribute__((address_space(3))) void*)&sa[bb][i*512], 16, 0, 0);
    }
  };
  stage(0, 0);
  __syncthreads();

  for (int ch = 0; ch < 16; ch++){
    const int bb = ch & 1;
    if (ch + 1 < 16) stage(bb ^ 1, ch + 1);
    #pragma unroll
    for (int kk = 0; kk < 2; kk++){
      const int ksg = ch*2 + kk;
      bf16x8 bfr[4];
      #pragma unroll
      for (int nj = 0; nj < 4; nj++){
        const int cg = bn*8 + wn*4 + nj;
        bfr[nj] = *(const bf16x8*)(Bp + ((size_t)(cg*32 + ksg)*64 + l)*8);
      }
      #pragma unroll
      for (int mi = 0; mi < 4; mi++){
        const int row = wm*64 + mi*16 + lrow;
        const int unit = kk*4 + lg;
        bf16x8 afr = *(const bf16x8*)&sa[bb][(row*8 + (unit ^ (row & 7)))*8];
        #pragma unroll
        for (int nj = 0; nj < 4; nj++)
          acc[mi][nj] = __builtin_amdgcn_mfma_f32_16x16x32_bf16(afr, bfr[nj], acc[mi][nj], 0, 0, 0);
      }
    }
    __syncthreads();
  }
  #pragma unroll
  for (int mi = 0; mi < 4; mi++)
    #pragma unroll
    for (int nj = 0; nj < 4; nj++)
      #pragma unroll
      for (int r = 0; r < 4; r++){
        const int row = bm*128 + wm*64 + mi*16 + lg*4 + r;
        const int col = bn*128 + wn*64 + nj*16 + lrow;
        C[(size_t)row*G4H + col] = f2bf(acc[mi][nj][r] + bias[col]);
      }
}

// ---- one LSTM timestep: z = [A1|A2] @ W (+ bias) (+ zin_t) ; gates ; c,h update ----
// Grid 256, XCD-swizzled: xcd=blk&7 owns nb in [xcd*8, xcd*8+8) -> W slice L2-resident.
template<int K1, int KTOT>
__global__ __launch_bounds__(512, 2)
void step_kernel(const unsigned short* __restrict__ A1,
                 const unsigned short* __restrict__ A2,
                 const unsigned short* __restrict__ Wpk,
                 const float* __restrict__ bias,          // nullable
                 const unsigned short* __restrict__ zin,  // nullable, [B][4096] bf16 (t-slice)
                 float* __restrict__ cst,
                 unsigned short* __restrict__ hbf_out,
                 float* __restrict__ hf_out)              // nullable
{
  constexpr int KST_TOT = KTOT/32;
  constexpr int NCH = (KTOT + 511)/512;
  __shared__ union SM {
    unsigned short a[2][32*512];
    float e[4*32*18];
  } sm;
  const int tid = threadIdx.x;
  const int w = tid >> 6, l = tid & 63;
  const int blk = blockIdx.x;
  const int q = blk >> 3;
  const int nb = (blk & 7)*8 + (q & 7);      // XCD (blk&7) serves 8 consecutive nb
  const int mb = q >> 3;
  const int mf = w & 1, cgi = w >> 1;
  const int cgg = nb*4 + cgi;
  const int lrow = l & 15, lg = l >> 4;

  f32x4 acc = {0.f, 0.f, 0.f, 0.f};

  auto stage = [&](int bb, int ch, int kw, int lu){
    const int nissue = kw >> 4;
    for (int i = w; i < nissue; i += 8){
      const int s = i*64 + l;
      const int row = s >> lu;
      const int uu  = s & ((1 << lu) - 1);
      const int ku  = uu ^ (row & 7);
      const int kg  = ch*512 + ku*8;
      const int R   = mb*32 + row;
      const unsigned short* src = (kg < K1) ? (A1 + (size_t)R*K1 + kg)
                                            : (A2 + (size_t)R*Hn + (kg - K1));
      __builtin_amdgcn_global_load_lds(
        (const __attribute__((address_space(1))) void*)src,
        (__attribute__((address_space(3))) void*)&sm.a[bb][i*512], 16, 0, 0);
    }
  };

  {
    constexpr int kw0 = (KTOT >= 512) ? 512 : KTOT;
    stage(0, 0, kw0, (kw0 == 512) ? 6 : 4);
  }
  __syncthreads();

  #pragma unroll
  for (int ch = 0; ch < NCH; ch++){
    const int bb = ch & 1;
    const int kw = ((KTOT - ch*512) >= 512) ? 512 : (KTOT - ch*512);
    if (ch + 1 < NCH){
      const int kwn = ((KTOT - (ch+1)*512) >= 512) ? 512 : (KTOT - (ch+1)*512);
      stage(bb ^ 1, ch+1, kwn, (kwn == 512) ? 6 : 4);
    }
    const int UPR  = kw >> 3;
    const int kstc = kw >> 5;
    const int row  = mf*16 + lrow;
    const unsigned short* wp = Wpk + ((size_t)(cgg*KST_TOT + ch*16)*64 + l)*8;
    #pragma unroll
    for (int ks = 0; ks < kstc; ks++){
      const int unit = ks*4 + lg;
      bf16x8 af = *(const bf16x8*)&sm.a[bb][(row*UPR + (unit ^ (row & 7)))*8];
      bf16x8 bw = *(const bf16x8*)(wp + (size_t)ks*512);
      acc = __builtin_amdgcn_mfma_f32_16x16x32_bf16(af, bw, acc, 0, 0, 0);
    }
    __syncthreads();
  }

  {
    const int jj = l & 15;
    #pragma unroll
    for (int r = 0; r < 4; r++){
      const int row = mf*16 + lg*4 + r;
      sm.e[(cgi*32 + row)*18 + jj] = acc[r];
    }
  }
  __syncthreads();
  {
    const int row = tid >> 4, jj = tid & 15;
    const int R = mb*32 + row;
    const int J = nb*16 + jj;
    float zi = sm.e[(0*32+row)*18 + jj];
    float zf = sm.e[(1*32+row)*18 + jj];
    float zo = sm.e[(2*32+row)*18 + jj];
    float zg = sm.e[(3*32+row)*18 + jj];
    if (bias){
      zi += bias[0*Hn + J]; zf += bias[1*Hn + J];
      zo += bias[2*Hn + J]; zg += bias[3*Hn + J];
    }
    if (zin){
      const size_t zb = (size_t)R*G4H + J;
      zi += bf2f(zin[zb + 0*Hn]); zf += bf2f(zin[zb + 1*Hn]);
      zo += bf2f(zin[zb + 2*Hn]); zg += bf2f(zin[zb + 3*Hn]);
    }
    const float gi = 1.f/(1.f + __expf(-zi));
    const float gf = 1.f/(1.f + __expf(-zf));
    const float go = 1.f/(1.f + __expf(-zo));
    const float gg = tanhf(zg);
    const size_t idx = (size_t)R*Hn + J;
    const float cn = gf * cst[idx] + gi * gg;
    cst[idx] = cn;
    const float hn = go * tanhf(cn);
    hbf_out[idx] = f2bf(hn);
    if (hf_out) hf_out[idx] = hn;
  }
}

// ---- final FC + copy h,c to d_out ----
__global__ __launch_bounds__(256)
void fc_out_kernel(const float* __restrict__ hf, const float* __restrict__ cst,
                   const float* __restrict__ fcw, const float* __restrict__ fcb,
                   float* __restrict__ dout){
  __shared__ float hrow[Hn];
  const int b = blockIdx.x, tid = threadIdx.x;
  for (int i = tid; i < Hn; i += 256) hrow[i] = hf[(size_t)b*Hn + i];
  __syncthreads();
  if (tid < PRED){
    float a = fcb[tid];
    for (int k = 0; k < Hn; k++) a += hrow[k] * fcw[(size_t)k*PRED + tid];
    dout[(size_t)b*PRED + tid] = tanhf(a);
  }
  for (int i = tid; i < Hn; i += 256){
    dout[Bsz*PRED + (size_t)b*Hn + i] = hf[(size_t)b*Hn + i];
    dout[Bsz*PRED + (size_t)Bsz*Hn + (size_t)b*Hn + i] = cst[(size_t)b*Hn + i];
  }
}

extern "C" void kernel_launch(void* const* d_in, const int* in_sizes, int n_in,
                              void* d_out, int out_size, void* d_ws, size_t ws_size,
                              hipStream_t stream){
  const float* x   = (const float*)d_in[0];
  const float* W0  = (const float*)d_in[1];
  const float* b0  = (const float*)d_in[2];
  const float* W1  = (const float*)d_in[3];
  const float* b1  = (const float*)d_in[4];
  const float* fcw = (const float*)d_in[5];
  const float* fcb = (const float*)d_in[6];
  float* dout = (float*)d_out;

  char* p = (char*)d_ws;
  auto alloc = [&](size_t bytes)->void*{
    void* r = (void*)p; p += (bytes + 255) & ~(size_t)255; return r;
  };
  unsigned short* xp   = (unsigned short*)alloc((size_t)SEQn*Bsz*NUMS*2);      // 8 MB
  unsigned short* Wpk0 = (unsigned short*)alloc((size_t)256*36*64*8*2);        // 9.4 MB
  unsigned short* H0   = (unsigned short*)alloc((size_t)(SEQn+1)*Bsz*Hn*2);    // 67 MB
  unsigned short* h1   = (unsigned short*)alloc((size_t)2*Bsz*Hn*2);
  float* cst = (float*)alloc((size_t)Bsz*Hn*4);
  float* hf  = (float*)alloc((size_t)Bsz*Hn*4);

  const bool big = ws_size >= (size_t)380*1024*1024;

  pack_x_kernel<<<dim3(SEQn/64, NUMS/64, Bsz), dim3(256), 0, stream>>>(x, xp);
  pack_w_kernel<<<dim3((256*36*64 + 255)/256), dim3(256), 0, stream>>>(W0, Wpk0, 36, 0, 1);
  zero_kernel<<<dim3((Bsz*Hn + 255)/256), dim3(256), 0, stream>>>(H0, cst);

  unsigned short *Wh1 = nullptr, *Wt1 = nullptr, *zin1 = nullptr, *Wpk1 = nullptr;
  if (big){
    Wh1  = (unsigned short*)alloc((size_t)256*32*64*8*2);                      // 8.4 MB
    Wt1  = (unsigned short*)alloc((size_t)256*32*64*8*2);                      // 8.4 MB
    zin1 = (unsigned short*)alloc((size_t)SEQn*Bsz*G4H*2);                     // 268 MB
    pack_w_kernel<<<dim3((256*32*64 + 255)/256), dim3(256), 0, stream>>>(W1, Wh1, 32, 1024, 1);
    pack_w_kernel<<<dim3((256*32*64 + 255)/256), dim3(256), 0, stream>>>(W1, Wt1, 32, 0, 0);
  } else {
    Wpk1 = (unsigned short*)alloc((size_t)256*64*64*8*2);                      // 16.8 MB
    pack_w_kernel<<<dim3((256*64*64 + 255)/256), dim3(256), 0, stream>>>(W1, Wpk1, 64, 0, 1);
  }

  // layer 0: A = [x_t (128) | h_prev (1024)], h ring in H0 (slot t -> t+1)
  for (int t = 0; t < SEQn; t++){
    step_kernel<128, 1152><<<dim3(256), dim3(512), 0, stream>>>(
        xp + (size_t)t*Bsz*NUMS,
        H0 + (size_t)t*Bsz*Hn,
        Wpk0, b0, nullptr, cst,
        H0 + (size_t)(t+1)*Bsz*Hn,
        (float*)nullptr);
  }

  if (big){
    // bulk: zin1[t][b][4096] = h0_t @ W1_top + b1   (A rows = H0 slots 1..256)
    in_gemm_kernel<<<dim3(256, 32), dim3(256), 0, stream>>>(
        H0 + (size_t)Bsz*Hn, Wt1, b1, zin1);
    for (int t = 0; t < SEQn; t++){
      const unsigned short* hprev = (t == 0) ? (H0 + (size_t)SEQn*Bsz*Hn)
                                             : (h1 + (size_t)((t+1)&1)*Bsz*Hn);
      step_kernel<1024, 1024><<<dim3(256), dim3(512), 0, stream>>>(
          hprev, nullptr, Wh1, nullptr,
          zin1 + (size_t)t*Bsz*G4H, cst,
          h1 + (size_t)(t&1)*Bsz*Hn, hf);
    }
  } else {
    for (int t = 0; t < SEQn; t++){
      const unsigned short* hprev = (t == 0) ? (H0 + (size_t)SEQn*Bsz*Hn)
                                             : (h1 + (size_t)((t+1)&1)*Bsz*Hn);
      step_kernel<1024, 2048><<<dim3(256), dim3(512), 0, stream>>>(
          H0 + (size_t)(t+1)*Bsz*Hn, hprev, Wpk1, b1, nullptr, cst,
          h1 + (size_t)(t&1)*Bsz*Hn, hf);
    }
  }
  fc_out_kernel<<<dim3(Bsz), dim3(256), 0, stream>>>(hf, cst, fcw, fcb, dout);
}